// Round 16
// baseline (233.119 us; speedup 1.0000x reference)
//
#include <hip/hip_runtime.h>

#define NPTS   20000
#define NCHUNK 313   // ceil(NPTS/64)
#define MAGIC  0x5CA17E57u

typedef __bf16 bf16x8 __attribute__((ext_vector_type(8)));
typedef float  f32x4  __attribute__((ext_vector_type(4)));

__device__ __forceinline__ unsigned short f2b(float f) {
    __bf16 h = (__bf16)f;                       // RNE fptrunc (hw cvt on gfx950)
    union { __bf16 h; unsigned short s; } u; u.h = h; return u.s;
}
__device__ __forceinline__ unsigned int pk2(float a, float b) {
    return (unsigned int)f2b(a) | ((unsigned int)f2b(b) << 16);
}
// force a block-uniform float into an SGPR (saves VGPRs for per-seed consts)
__device__ __forceinline__ float rfl(float x) {
    return __int_as_float(__builtin_amdgcn_readfirstlane(__float_as_int(x)));
}

// ---------------- workspace layout ----------------
#define WS_BINNED    0          // 40000 float4 = 640000 B
#define WS_PARTHIST  640000     // 40*512 u32  =  81920 B
#define WS_COUNTS    721920     // 1024 u32
#define WS_OFFSETS   726016     // 1024 u32
#define WS_FLAGS     730112     // 40 u32 (poison 0xAAAAAAAA != MAGIC) [pad 256]
#define WS_W2P       730368     // 128*64  bf16 = 16384 B (BN2-scaled, packed)
#define WS_W3P       746752     // 256*128 bf16 = 65536 B (BN3-scaled, packed)
#define WS_W1E       812288     // 64*3 f32
#define WS_B1E       813056     // 64 f32
#define WS_B2E       813312     // 128 f32
#define WS_B3E       813824     // 256 f32

// =============== prep: binning + one-time weight pre-pack ==================
__global__ __launch_bounds__(512)
void bin_kernel(const float* __restrict__ pointcloud,
                const float* __restrict__ w1,
                const float* __restrict__ g1,  const float* __restrict__ be1,
                const float* __restrict__ mn1, const float* __restrict__ vr1,
                const float* __restrict__ w2,
                const float* __restrict__ g2,  const float* __restrict__ be2,
                const float* __restrict__ mn2, const float* __restrict__ vr2,
                const float* __restrict__ w3,
                const float* __restrict__ g3,  const float* __restrict__ be3,
                const float* __restrict__ mn3, const float* __restrict__ vr3,
                unsigned int* __restrict__ parthist,
                unsigned int* __restrict__ counts,
                unsigned int* __restrict__ offsets,
                unsigned int* __restrict__ flags,
                float4* __restrict__ binned,
                unsigned short* __restrict__ w2p,
                unsigned short* __restrict__ w3p,
                float* __restrict__ w1e_g, float* __restrict__ b1e_g,
                float* __restrict__ b2e_g, float* __restrict__ b3e_g)
{
    __shared__ unsigned int h[512];
    __shared__ unsigned int scanv[512];
    __shared__ unsigned int cur[512];
    const int blk = blockIdx.x;          // 0..39
    const int b   = blk / 20;
    const int p   = blk % 20;
    const int tid = threadIdx.x;
    const int gid = blk * 512 + tid;     // 0..20479

    // ---- weight pre-pack (spread across all threads) ----
    for (int e = gid; e < 8192; e += 20480) {          // w2p[128][64]
        int row = e >> 6;
        float inv = g2[row] / sqrtf(vr2[row] + 1e-5f);
        w2p[e] = f2b(w2[e] * inv);
    }
    for (int e = gid; e < 32768; e += 20480) {         // w3p[256][128]
        int row = e >> 7;
        float inv = g3[row] / sqrtf(vr3[row] + 1e-5f);
        w3p[e] = f2b(w3[e] * inv);
    }
    if (gid < 64) {
        float inv = g1[gid] / sqrtf(vr1[gid] + 1e-5f);
        w1e_g[gid*3+0] = inv * w1[gid*3+0];
        w1e_g[gid*3+1] = inv * w1[gid*3+1];
        w1e_g[gid*3+2] = inv * w1[gid*3+2];
        b1e_g[gid]     = be1[gid] - mn1[gid] * inv;
    }
    if (gid < 128) {
        float inv = g2[gid] / sqrtf(vr2[gid] + 1e-5f);
        b2e_g[gid] = be2[gid] - mn2[gid] * inv;
    }
    if (gid < 256) {
        float inv = g3[gid] / sqrtf(vr3[gid] + 1e-5f);
        b3e_g[gid] = be3[gid] - mn3[gid] * inv;
    }

    // ---- histogram of own slice ----
    h[tid] = 0;
    __syncthreads();

    const float* base = pointcloud + (b * NPTS + p * 1000) * 3;
    for (int i = tid; i < 1000; i += 512) {
        float x = base[i*3+0], y = base[i*3+1], z = base[i*3+2];
        int cx = min(7, (int)(x * 16.0f));
        int cy = min(7, (int)(y * 16.0f));
        int cz = min(7, (int)(z * 16.0f));
        atomicAdd(&h[(cz * 8 + cy) * 8 + cx], 1u);
    }
    __syncthreads();

    atomicExch(&parthist[blk * 512 + tid], h[tid]);
    __syncthreads();
    __threadfence();
    if (tid == 0) atomicExch(&flags[blk], MAGIC);

    if (tid < 40) {
        while (atomicAdd(&flags[tid], 0u) != MAGIC) { }
    }
    __syncthreads();
    __threadfence();

    unsigned int cnt = 0, partial = 0;
    #pragma unroll
    for (int pp = 0; pp < 20; ++pp) {
        unsigned int v = atomicAdd(&parthist[(b * 20 + pp) * 512 + tid], 0u);
        cnt += v;
        if (pp < p) partial += v;
    }
    scanv[tid] = cnt;
    __syncthreads();
    #pragma unroll
    for (int off = 1; off < 512; off <<= 1) {
        unsigned int v = 0;
        if (tid >= off) v = scanv[tid - off];
        __syncthreads();
        scanv[tid] += v;
        __syncthreads();
    }
    unsigned int excl = scanv[tid] - cnt;
    if (p == 0) {
        counts [b * 512 + tid] = cnt;
        offsets[b * 512 + tid] = b * NPTS + excl;
    }
    cur[tid] = b * NPTS + excl + partial;
    __syncthreads();

    for (int i = tid; i < 1000; i += 512) {
        float x = base[i*3+0], y = base[i*3+1], z = base[i*3+2];
        int cx = min(7, (int)(x * 16.0f));
        int cy = min(7, (int)(y * 16.0f));
        int cz = min(7, (int)(z * 16.0f));
        int cid = (cz * 8 + cy) * 8 + cx;
        unsigned int slot = atomicAdd(&cur[cid], 1u);
        binned[slot] = make_float4(x, y, z, __int_as_float(p * 1000 + i));
    }
}

// =============== FUSED grid-scan + MLP =====================================
// R16 = R15 + VGPR diet: (1) L3 bias moved to the final epilogue (valid since
// max_s relu(b+x_s) = relu(b + max_s x_s); also matches numpy's dot-then-BN
// order) -> binit3's 16 regs freed in the hottest phase; rm init = -inf.
// (2) per-seed constants forced to SGPRs via readfirstlane (block-uniform).
// Goal: VGPR <= 102 -> 5 blocks/CU (LDS 28672 already allows 5).
struct __align__(16) SMemF {
    union {
        struct {
            unsigned int bm[4][640];    // 10240 B: 313 u64-words as u32 pairs
            int cstart[64];             // ncell can reach 64 (R7 bug)
            int ccnt[64];
        } a;
        struct {
            unsigned short h1[64][72];  //  9216 B [sample][ch] +8 pad
            unsigned short h2[64][136]; // 17408 B [sample][ch] +8 pad
        } b;
    } u;
    int    idxs[4][64];
    float  w1e[64][3];                  // BN1-absorbed layer-1 weights
    float  b1e[64];
};

// NOTE: min-waves stays 2 — NO forced VGPR cap (R4: forced caps spill
// catastrophically). Occupancy gain must come from genuine reg reduction.
__global__ __launch_bounds__(256, 2)
void fused_kernel(const float* __restrict__ seed_xyz,
                  const float* __restrict__ pointcloud,
                  const float* __restrict__ vp_rot,
                  const unsigned int* __restrict__ counts,
                  const unsigned int* __restrict__ offsets,
                  const float4* __restrict__ binned,
                  const unsigned short* __restrict__ w2p,
                  const unsigned short* __restrict__ w3p,
                  const float* __restrict__ w1e_g, const float* __restrict__ b1e_g,
                  const float* __restrict__ b2e_g, const float* __restrict__ b3e_g,
                  float* __restrict__ out)
{
    __shared__ SMemF sm;
    const int tid = threadIdx.x;
    const int wv  = tid >> 6;
    const int ln  = tid & 63;
    const int q   = ln >> 4;
    const int l15 = ln & 15;

    // XCD-aware swizzle: blocks writing the same output cache line (s..s+3)
    // share blk&7 -> same XCD under round-robin dispatch.
    const int blk = blockIdx.x;
    const int i8  = blk >> 3;
    const int s   = (blk & 7) * 128 + (i8 & 127);
    const int b   = i8 >> 7;
    const int bs  = b * 1024 + s;

    // ---- L1 constants from ws ----
    if (tid < 64) {
        sm.w1e[tid][0] = w1e_g[tid*3+0];
        sm.w1e[tid][1] = w1e_g[tid*3+1];
        sm.w1e[tid][2] = w1e_g[tid*3+2];
        sm.b1e[tid]    = b1e_g[tid];
    }

    // ---- zero bitmaps (2560 u32 = bm[4][640]) ----
    {
        unsigned int* bmp = &sm.u.a.bm[0][0];
        #pragma unroll
        for (int i = 0; i < 10; ++i) bmp[tid + i * 256] = 0;
    }

    // per-seed constants in SGPRs (block-uniform loads)
    const float sx = rfl(seed_xyz[bs*3+0]);
    const float sy = rfl(seed_xyz[bs*3+1]);
    const float sz = rfl(seed_xyz[bs*3+2]);
    const float R00 = rfl(vp_rot[bs*9+0]), R01 = rfl(vp_rot[bs*9+1]), R02 = rfl(vp_rot[bs*9+2]);
    const float R10 = rfl(vp_rot[bs*9+3]), R11 = rfl(vp_rot[bs*9+4]), R12 = rfl(vp_rot[bs*9+5]);
    const float R20 = rfl(vp_rot[bs*9+6]), R21 = rfl(vp_rot[bs*9+7]), R22 = rfl(vp_rot[bs*9+8]);

    // candidate cell range: cells overlapping [s-0.066, s+0.066]^3
    // (each dim spans 3 OR 4 cells -> ncell up to 64; R7 post-mortem)
    const int lx = max(0, (int)floorf((sx - 0.066f) * 16.f));
    const int hx = min(7, (int)floorf((sx + 0.066f) * 16.f));
    const int ly = max(0, (int)floorf((sy - 0.066f) * 16.f));
    const int hy = min(7, (int)floorf((sy + 0.066f) * 16.f));
    const int lz = max(0, (int)floorf((sz - 0.066f) * 16.f));
    const int hz = min(7, (int)floorf((sz + 0.066f) * 16.f));
    const int nx = hx - lx + 1, ny = hy - ly + 1, nz = hz - lz + 1;
    const int ncell = nx * ny * nz;     // <= 64

    if (tid < ncell) {
        int cz = lz + tid / (nx * ny);
        int rem = tid % (nx * ny);
        int cy = ly + rem / nx;
        int cx = lx + rem % nx;
        int cid = (cz * 8 + cy) * 8 + cx;
        sm.u.a.cstart[tid] = (int)offsets[b * 512 + cid];
        sm.u.a.ccnt[tid]   = (int)counts [b * 512 + cid];
    }
    __syncthreads();

    // ---- scan: cell-outer (wave wv takes cells wv, wv+4, ...), point-inner.
    // Mask uses exact fp32 contract(off) arithmetic; bits set order-
    // independently -> stage B semantics identical to brute-force.
    {
        #pragma clang fp contract(off)
        for (int k = wv; k < ncell; k += 4) {
            const int base = sm.u.a.cstart[k];
            const int cnt  = sm.u.a.ccnt[k];
            for (int i = ln; i < cnt; i += 64) {
                float4 pt = binned[base + i];
                float rx = pt.x - sx, ry = pt.y - sy, rz = pt.z - sz;
                float x = (rx*R00 + ry*R10) + rz*R20;
                float y = (rx*R01 + ry*R11) + rz*R21;
                float z = (rx*R02 + ry*R12) + rz*R22;
                if (((y*y + z*z) < 0.0025f) && (x > -0.02f) && (x < 0.04f)) {
                    int n = __float_as_int(pt.w);
                    unsigned int bit = 1u << (n & 31);
                    int wi = n >> 5;
                    if (x < 0.01f) atomicOr(&sm.u.a.bm[0][wi], bit);
                    if (x < 0.02f) atomicOr(&sm.u.a.bm[1][wi], bit);
                    if (x < 0.03f) atomicOr(&sm.u.a.bm[2][wi], bit);
                    atomicOr(&sm.u.a.bm[3][wi], bit);
                }
            }
        }
    }
    __syncthreads();

    // ---- stage B: ordered first-64 extraction (wave wv -> d=wv) ----
    {
        const int d = wv;
        int carry = 0;
        for (int r = 0; r < 5 && carry < 64; ++r) {
            int c = r*64 + ln;
            unsigned long long w = 0ULL;
            if (c < NCHUNK)
                w = ((unsigned long long)sm.u.a.bm[d][2*c+1] << 32)
                  |  (unsigned long long)sm.u.a.bm[d][2*c];
            int wc = __popcll(w);
            int incl = wc;
            #pragma unroll
            for (int off = 1; off < 64; off <<= 1) {
                int t = __shfl_up(incl, off);
                if (ln >= off) incl += t;
            }
            int rank  = carry + incl - wc;
            int total = __shfl(incl, 63);
            while (w && rank < 64) {
                int bp = __builtin_ctzll(w);
                w &= w - 1;
                sm.idxs[d][rank] = c*64 + bp;
                ++rank;
            }
            carry += total;
        }
        int cnt = carry < 64 ? carry : 64;
        int first = (cnt > 0) ? sm.idxs[d][0] : 0;
        if (ln >= cnt) sm.idxs[d][ln] = first;
    }

    // ---- A-fragments: direct dwordx4 loads of pre-packed, BN-scaled bf16 --
    bf16x8 aw2[2][2], aw3[4][4];
    #pragma unroll
    for (int m = 0; m < 2; ++m) {
        int row = (wv*2+m)*16 + l15;
        #pragma unroll
        for (int kk = 0; kk < 2; ++kk)
            aw2[m][kk] = *(const bf16x8*)(w2p + row*64 + kk*32 + q*8);
    }
    #pragma unroll
    for (int m = 0; m < 4; ++m) {
        int row = (wv*4+m)*16 + l15;
        #pragma unroll
        for (int kk = 0; kk < 4; ++kk)
            aw3[m][kk] = *(const bf16x8*)(w3p + row*128 + kk*32 + q*8);
    }

    __syncthreads();    // idxs visible; bm/cstart/ccnt dead -> h1/h2 may reuse

    // L1(d): lane ln recomputes rel_rot of idxs[d][ln] (exact contract(off)
    // arithmetic), then 16 channels of BN1-absorbed fma -> h1[ln][wv*16..].
    auto do_l1 = [&](int d) {
        int n = sm.idxs[d][ln];
        const float* p = pointcloud + (b*NPTS + n)*3;
        float x0, x1, x2;
        {
            #pragma clang fp contract(off)
            float rx = p[0] - sx, ry = p[1] - sy, rz = p[2] - sz;
            x0 = (rx*R00 + ry*R10) + rz*R20;
            x1 = (rx*R01 + ry*R11) + rz*R21;
            x2 = (rx*R02 + ry*R12) + rz*R22;
        }
        unsigned int pk[8];
        #pragma unroll
        for (int i = 0; i < 8; ++i) {
            int ch = wv*16 + i*2;
            float ha = fmaf(x0, sm.w1e[ch][0],
                       fmaf(x1, sm.w1e[ch][1],
                       fmaf(x2, sm.w1e[ch][2], sm.b1e[ch])));
            float hb = fmaf(x0, sm.w1e[ch+1][0],
                       fmaf(x1, sm.w1e[ch+1][1],
                       fmaf(x2, sm.w1e[ch+1][2], sm.b1e[ch+1])));
            pk[i] = pk2(fmaxf(ha, 0.f), fmaxf(hb, 0.f));
        }
        *(uint4*)&sm.u.b.h1[ln][wv*16 + 0] = make_uint4(pk[0], pk[1], pk[2], pk[3]);
        *(uint4*)&sm.u.b.h1[ln][wv*16 + 8] = make_uint4(pk[4], pk[5], pk[6], pk[7]);
    };

    do_l1(0);
    __syncthreads();

    for (int d = 0; d < 4; ++d) {
        // layer 2: M=128, K=64, N=64; acc init = BN2 bias (global, L2-hot)
        {
            f32x4 binit2[2];
            #pragma unroll
            for (int m = 0; m < 2; ++m)
                binit2[m] = *(const f32x4*)&b2e_g[(wv*2+m)*16 + q*4];
            #pragma unroll
            for (int nt = 0; nt < 4; ++nt) {
                int n = nt*16 + l15;
                bf16x8 b0 = *(const bf16x8*)&sm.u.b.h1[n][q*8];
                bf16x8 b1 = *(const bf16x8*)&sm.u.b.h1[n][32 + q*8];
                #pragma unroll
                for (int m = 0; m < 2; ++m) {
                    f32x4 acc = binit2[m];
                    acc = __builtin_amdgcn_mfma_f32_16x16x32_bf16(aw2[m][0], b0, acc, 0, 0, 0);
                    acc = __builtin_amdgcn_mfma_f32_16x16x32_bf16(aw2[m][1], b1, acc, 0, 0, 0);
                    int ch0 = (wv*2+m)*16 + q*4;
                    uint2 pkk;
                    pkk.x = pk2(fmaxf(acc[0], 0.f), fmaxf(acc[1], 0.f));
                    pkk.y = pk2(fmaxf(acc[2], 0.f), fmaxf(acc[3], 0.f));
                    *(uint2*)&sm.u.b.h2[n][ch0] = pkk;
                }
            }
        }
        __syncthreads();

        // layer 3: M=256, K=128; acc init = 0, bias applied in epilogue
        // (valid: max_s relu(b + x_s) = relu(b + max_s x_s); rm init = -inf).
        {
            float rm[4][4];
            #pragma unroll
            for (int m = 0; m < 4; ++m)
                #pragma unroll
                for (int r = 0; r < 4; ++r) rm[m][r] = -1e30f;

            #pragma unroll
            for (int nt = 0; nt < 4; ++nt) {
                int n = nt*16 + l15;
                bf16x8 bb0 = *(const bf16x8*)&sm.u.b.h2[n][ 0 + q*8];
                bf16x8 bb1 = *(const bf16x8*)&sm.u.b.h2[n][32 + q*8];
                bf16x8 bb2 = *(const bf16x8*)&sm.u.b.h2[n][64 + q*8];
                bf16x8 bb3 = *(const bf16x8*)&sm.u.b.h2[n][96 + q*8];
                #pragma unroll
                for (int m = 0; m < 4; ++m) {
                    f32x4 acc = {0.f, 0.f, 0.f, 0.f};
                    acc = __builtin_amdgcn_mfma_f32_16x16x32_bf16(aw3[m][0], bb0, acc, 0, 0, 0);
                    acc = __builtin_amdgcn_mfma_f32_16x16x32_bf16(aw3[m][1], bb1, acc, 0, 0, 0);
                    acc = __builtin_amdgcn_mfma_f32_16x16x32_bf16(aw3[m][2], bb2, acc, 0, 0, 0);
                    acc = __builtin_amdgcn_mfma_f32_16x16x32_bf16(aw3[m][3], bb3, acc, 0, 0, 0);
                    #pragma unroll
                    for (int r = 0; r < 4; ++r)
                        rm[m][r] = fmaxf(rm[m][r], acc[r]);
                }
            }

            if (d < 3) do_l1(d + 1);

            #pragma unroll
            for (int m = 0; m < 4; ++m) {
                #pragma unroll
                for (int r = 0; r < 4; ++r) {
                    float v = rm[m][r];
                    v = fmaxf(v, __shfl_xor(v, 1));
                    v = fmaxf(v, __shfl_xor(v, 2));
                    v = fmaxf(v, __shfl_xor(v, 4));
                    v = fmaxf(v, __shfl_xor(v, 8));
                    if (l15 == 0) {
                        int ch = (wv*4+m)*16 + q*4 + r;
                        float o = fmaxf(v + b3e_g[ch], 0.f);
                        out[((b*256 + ch)*1024 + s)*4 + d] = o;
                    }
                }
            }
        }
        if (d < 3) __syncthreads();
    }
}

extern "C" void kernel_launch(void* const* d_in, const int* in_sizes, int n_in,
                              void* d_out, int out_size, void* d_ws, size_t ws_size,
                              hipStream_t stream) {
    (void)in_sizes; (void)n_in; (void)out_size; (void)ws_size;
    const float* seed = (const float*)d_in[0];
    const float* pc   = (const float*)d_in[1];
    const float* rot  = (const float*)d_in[2];
    const float* w1   = (const float*)d_in[3];
    const float* g1   = (const float*)d_in[4];
    const float* be1  = (const float*)d_in[5];
    const float* mn1  = (const float*)d_in[6];
    const float* vr1  = (const float*)d_in[7];
    const float* w2   = (const float*)d_in[8];
    const float* g2   = (const float*)d_in[9];
    const float* be2  = (const float*)d_in[10];
    const float* mn2  = (const float*)d_in[11];
    const float* vr2  = (const float*)d_in[12];
    const float* w3   = (const float*)d_in[13];
    const float* g3   = (const float*)d_in[14];
    const float* be3  = (const float*)d_in[15];
    const float* mn3  = (const float*)d_in[16];
    const float* vr3  = (const float*)d_in[17];

    char* ws = (char*)d_ws;
    float4*         binned   = (float4*)(ws + WS_BINNED);
    unsigned int*   parthist = (unsigned int*)(ws + WS_PARTHIST);
    unsigned int*   counts   = (unsigned int*)(ws + WS_COUNTS);
    unsigned int*   offsets  = (unsigned int*)(ws + WS_OFFSETS);
    unsigned int*   flags    = (unsigned int*)(ws + WS_FLAGS);
    unsigned short* w2p      = (unsigned short*)(ws + WS_W2P);
    unsigned short* w3p      = (unsigned short*)(ws + WS_W3P);
    float*          w1e_g    = (float*)(ws + WS_W1E);
    float*          b1e_g    = (float*)(ws + WS_B1E);
    float*          b2e_g    = (float*)(ws + WS_B2E);
    float*          b3e_g    = (float*)(ws + WS_B3E);

    bin_kernel  <<<dim3(40),   dim3(512), 0, stream>>>(
        pc,
        w1, g1, be1, mn1, vr1,
        w2, g2, be2, mn2, vr2,
        w3, g3, be3, mn3, vr3,
        parthist, counts, offsets, flags, binned,
        w2p, w3p, w1e_g, b1e_g, b2e_g, b3e_g);
    fused_kernel<<<dim3(2048), dim3(256), 0, stream>>>(
        seed, pc, rot, counts, offsets, binned,
        w2p, w3p, w1e_g, b1e_g, b2e_g, b3e_g,
        (float*)d_out);
}

// Round 17
// 217.431 us; speedup vs baseline: 1.0722x; 1.0722x over previous
//
#include <hip/hip_runtime.h>

#define NPTS   20000
#define NCHUNK 313   // ceil(NPTS/64)
#define MAGIC  0x5CA17E57u

typedef __bf16 bf16x8 __attribute__((ext_vector_type(8)));
typedef float  f32x4  __attribute__((ext_vector_type(4)));

__device__ __forceinline__ unsigned short f2b(float f) {
    __bf16 h = (__bf16)f;                       // RNE fptrunc (hw cvt on gfx950)
    union { __bf16 h; unsigned short s; } u; u.h = h; return u.s;
}
__device__ __forceinline__ unsigned int pk2(float a, float b) {
    return (unsigned int)f2b(a) | ((unsigned int)f2b(b) << 16);
}

// ---------------- workspace layout ----------------
#define WS_BINNED    0          // 40000 float4 = 640000 B
#define WS_PARTHIST  640000     // 40*512 u32  =  81920 B
#define WS_COUNTS    721920     // 1024 u32
#define WS_OFFSETS   726016     // 1024 u32
#define WS_FLAGS     730112     // 40 u32 (poison 0xAAAAAAAA != MAGIC) [pad 256]
#define WS_W2P       730368     // 128*64  bf16 = 16384 B (BN2-scaled, packed)
#define WS_W3P       746752     // 256*128 bf16 = 65536 B (BN3-scaled, packed)
#define WS_W1E       812288     // 64*3 f32
#define WS_B1E       813056     // 64 f32
#define WS_B2E       813312     // 128 f32
#define WS_B3E       813824     // 256 f32

// =============== prep: binning + one-time weight pre-pack ==================
__global__ __launch_bounds__(512)
void bin_kernel(const float* __restrict__ pointcloud,
                const float* __restrict__ w1,
                const float* __restrict__ g1,  const float* __restrict__ be1,
                const float* __restrict__ mn1, const float* __restrict__ vr1,
                const float* __restrict__ w2,
                const float* __restrict__ g2,  const float* __restrict__ be2,
                const float* __restrict__ mn2, const float* __restrict__ vr2,
                const float* __restrict__ w3,
                const float* __restrict__ g3,  const float* __restrict__ be3,
                const float* __restrict__ mn3, const float* __restrict__ vr3,
                unsigned int* __restrict__ parthist,
                unsigned int* __restrict__ counts,
                unsigned int* __restrict__ offsets,
                unsigned int* __restrict__ flags,
                float4* __restrict__ binned,
                unsigned short* __restrict__ w2p,
                unsigned short* __restrict__ w3p,
                float* __restrict__ w1e_g, float* __restrict__ b1e_g,
                float* __restrict__ b2e_g, float* __restrict__ b3e_g)
{
    __shared__ unsigned int h[512];
    __shared__ unsigned int scanv[512];
    __shared__ unsigned int cur[512];
    const int blk = blockIdx.x;          // 0..39
    const int b   = blk / 20;
    const int p   = blk % 20;
    const int tid = threadIdx.x;
    const int gid = blk * 512 + tid;     // 0..20479

    // ---- weight pre-pack (spread across all threads) ----
    for (int e = gid; e < 8192; e += 20480) {          // w2p[128][64]
        int row = e >> 6;
        float inv = g2[row] / sqrtf(vr2[row] + 1e-5f);
        w2p[e] = f2b(w2[e] * inv);
    }
    for (int e = gid; e < 32768; e += 20480) {         // w3p[256][128]
        int row = e >> 7;
        float inv = g3[row] / sqrtf(vr3[row] + 1e-5f);
        w3p[e] = f2b(w3[e] * inv);
    }
    if (gid < 64) {
        float inv = g1[gid] / sqrtf(vr1[gid] + 1e-5f);
        w1e_g[gid*3+0] = inv * w1[gid*3+0];
        w1e_g[gid*3+1] = inv * w1[gid*3+1];
        w1e_g[gid*3+2] = inv * w1[gid*3+2];
        b1e_g[gid]     = be1[gid] - mn1[gid] * inv;
    }
    if (gid < 128) {
        float inv = g2[gid] / sqrtf(vr2[gid] + 1e-5f);
        b2e_g[gid] = be2[gid] - mn2[gid] * inv;
    }
    if (gid < 256) {
        float inv = g3[gid] / sqrtf(vr3[gid] + 1e-5f);
        b3e_g[gid] = be3[gid] - mn3[gid] * inv;
    }

    // ---- histogram of own slice ----
    h[tid] = 0;
    __syncthreads();

    const float* base = pointcloud + (b * NPTS + p * 1000) * 3;
    for (int i = tid; i < 1000; i += 512) {
        float x = base[i*3+0], y = base[i*3+1], z = base[i*3+2];
        int cx = min(7, (int)(x * 16.0f));
        int cy = min(7, (int)(y * 16.0f));
        int cz = min(7, (int)(z * 16.0f));
        atomicAdd(&h[(cz * 8 + cy) * 8 + cx], 1u);
    }
    __syncthreads();

    atomicExch(&parthist[blk * 512 + tid], h[tid]);
    __syncthreads();
    __threadfence();
    if (tid == 0) atomicExch(&flags[blk], MAGIC);

    if (tid < 40) {
        while (atomicAdd(&flags[tid], 0u) != MAGIC) { }
    }
    __syncthreads();
    __threadfence();

    unsigned int cnt = 0, partial = 0;
    #pragma unroll
    for (int pp = 0; pp < 20; ++pp) {
        unsigned int v = atomicAdd(&parthist[(b * 20 + pp) * 512 + tid], 0u);
        cnt += v;
        if (pp < p) partial += v;
    }
    scanv[tid] = cnt;
    __syncthreads();
    #pragma unroll
    for (int off = 1; off < 512; off <<= 1) {
        unsigned int v = 0;
        if (tid >= off) v = scanv[tid - off];
        __syncthreads();
        scanv[tid] += v;
        __syncthreads();
    }
    unsigned int excl = scanv[tid] - cnt;
    if (p == 0) {
        counts [b * 512 + tid] = cnt;
        offsets[b * 512 + tid] = b * NPTS + excl;
    }
    cur[tid] = b * NPTS + excl + partial;
    __syncthreads();

    for (int i = tid; i < 1000; i += 512) {
        float x = base[i*3+0], y = base[i*3+1], z = base[i*3+2];
        int cx = min(7, (int)(x * 16.0f));
        int cy = min(7, (int)(y * 16.0f));
        int cz = min(7, (int)(z * 16.0f));
        int cid = (cz * 8 + cy) * 8 + cx;
        unsigned int slot = atomicAdd(&cur[cid], 1u);
        binned[slot] = make_float4(x, y, z, __int_as_float(p * 1000 + i));
    }
}

// =============== FUSED grid-scan + MLP =====================================
// R17 = R15 base (R16's rfl/bias-late reverted — measured −16us regression)
// + aw3 streaming: the 64-VGPR aw3 block is no longer held resident; L3 is
// restructured m-outer and loads one m-row of w3p (4x dwordx4, L2-broadcast)
// right before its 16 MFMAs. Goal: VGPR <= 102 -> 5 waves/SIMD.
struct __align__(16) SMemF {
    union {
        struct {
            unsigned int bm[4][640];    // 10240 B: 313 u64-words as u32 pairs
            int cstart[64];             // ncell can reach 64 (R7 bug)
            int ccnt[64];
        } a;
        struct {
            unsigned short h1[64][72];  //  9216 B [sample][ch] +8 pad
            unsigned short h2[64][136]; // 17408 B [sample][ch] +8 pad
        } b;
    } u;
    int    idxs[4][64];
    float  w1e[64][3];                  // BN1-absorbed layer-1 weights
    float  b1e[64];
};

// NOTE: min-waves stays 2 — NO forced VGPR cap (R4: forced caps spill
// catastrophically). Occupancy gain must come from genuine reg reduction.
__global__ __launch_bounds__(256, 2)
void fused_kernel(const float* __restrict__ seed_xyz,
                  const float* __restrict__ pointcloud,
                  const float* __restrict__ vp_rot,
                  const unsigned int* __restrict__ counts,
                  const unsigned int* __restrict__ offsets,
                  const float4* __restrict__ binned,
                  const unsigned short* __restrict__ w2p,
                  const unsigned short* __restrict__ w3p,
                  const float* __restrict__ w1e_g, const float* __restrict__ b1e_g,
                  const float* __restrict__ b2e_g, const float* __restrict__ b3e_g,
                  float* __restrict__ out)
{
    __shared__ SMemF sm;
    const int tid = threadIdx.x;
    const int wv  = tid >> 6;
    const int ln  = tid & 63;
    const int q   = ln >> 4;
    const int l15 = ln & 15;

    // XCD-aware swizzle: blocks writing the same output cache line (s..s+3)
    // share blk&7 -> same XCD under round-robin dispatch.
    const int blk = blockIdx.x;
    const int i8  = blk >> 3;
    const int s   = (blk & 7) * 128 + (i8 & 127);
    const int b   = i8 >> 7;
    const int bs  = b * 1024 + s;

    // ---- L1 constants from ws ----
    if (tid < 64) {
        sm.w1e[tid][0] = w1e_g[tid*3+0];
        sm.w1e[tid][1] = w1e_g[tid*3+1];
        sm.w1e[tid][2] = w1e_g[tid*3+2];
        sm.b1e[tid]    = b1e_g[tid];
    }

    // ---- zero bitmaps (2560 u32 = bm[4][640]) ----
    {
        unsigned int* bmp = &sm.u.a.bm[0][0];
        #pragma unroll
        for (int i = 0; i < 10; ++i) bmp[tid + i * 256] = 0;
    }

    const float sx = seed_xyz[bs*3+0];
    const float sy = seed_xyz[bs*3+1];
    const float sz = seed_xyz[bs*3+2];
    const float R00 = vp_rot[bs*9+0], R01 = vp_rot[bs*9+1], R02 = vp_rot[bs*9+2];
    const float R10 = vp_rot[bs*9+3], R11 = vp_rot[bs*9+4], R12 = vp_rot[bs*9+5];
    const float R20 = vp_rot[bs*9+6], R21 = vp_rot[bs*9+7], R22 = vp_rot[bs*9+8];

    // candidate cell range: cells overlapping [s-0.066, s+0.066]^3
    // (each dim spans 3 OR 4 cells -> ncell up to 64; R7 post-mortem)
    const int lx = max(0, (int)floorf((sx - 0.066f) * 16.f));
    const int hx = min(7, (int)floorf((sx + 0.066f) * 16.f));
    const int ly = max(0, (int)floorf((sy - 0.066f) * 16.f));
    const int hy = min(7, (int)floorf((sy + 0.066f) * 16.f));
    const int lz = max(0, (int)floorf((sz - 0.066f) * 16.f));
    const int hz = min(7, (int)floorf((sz + 0.066f) * 16.f));
    const int nx = hx - lx + 1, ny = hy - ly + 1, nz = hz - lz + 1;
    const int ncell = nx * ny * nz;     // <= 64

    if (tid < ncell) {
        int cz = lz + tid / (nx * ny);
        int rem = tid % (nx * ny);
        int cy = ly + rem / nx;
        int cx = lx + rem % nx;
        int cid = (cz * 8 + cy) * 8 + cx;
        sm.u.a.cstart[tid] = (int)offsets[b * 512 + cid];
        sm.u.a.ccnt[tid]   = (int)counts [b * 512 + cid];
    }
    __syncthreads();

    // ---- scan: cell-outer (wave wv takes cells wv, wv+4, ...), point-inner.
    // Mask uses exact fp32 contract(off) arithmetic; bits set order-
    // independently -> stage B semantics identical to brute-force.
    {
        #pragma clang fp contract(off)
        for (int k = wv; k < ncell; k += 4) {
            const int base = sm.u.a.cstart[k];
            const int cnt  = sm.u.a.ccnt[k];
            for (int i = ln; i < cnt; i += 64) {
                float4 pt = binned[base + i];
                float rx = pt.x - sx, ry = pt.y - sy, rz = pt.z - sz;
                float x = (rx*R00 + ry*R10) + rz*R20;
                float y = (rx*R01 + ry*R11) + rz*R21;
                float z = (rx*R02 + ry*R12) + rz*R22;
                if (((y*y + z*z) < 0.0025f) && (x > -0.02f) && (x < 0.04f)) {
                    int n = __float_as_int(pt.w);
                    unsigned int bit = 1u << (n & 31);
                    int wi = n >> 5;
                    if (x < 0.01f) atomicOr(&sm.u.a.bm[0][wi], bit);
                    if (x < 0.02f) atomicOr(&sm.u.a.bm[1][wi], bit);
                    if (x < 0.03f) atomicOr(&sm.u.a.bm[2][wi], bit);
                    atomicOr(&sm.u.a.bm[3][wi], bit);
                }
            }
        }
    }
    __syncthreads();

    // ---- stage B: ordered first-64 extraction (wave wv -> d=wv) ----
    {
        const int d = wv;
        int carry = 0;
        for (int r = 0; r < 5 && carry < 64; ++r) {
            int c = r*64 + ln;
            unsigned long long w = 0ULL;
            if (c < NCHUNK)
                w = ((unsigned long long)sm.u.a.bm[d][2*c+1] << 32)
                  |  (unsigned long long)sm.u.a.bm[d][2*c];
            int wc = __popcll(w);
            int incl = wc;
            #pragma unroll
            for (int off = 1; off < 64; off <<= 1) {
                int t = __shfl_up(incl, off);
                if (ln >= off) incl += t;
            }
            int rank  = carry + incl - wc;
            int total = __shfl(incl, 63);
            while (w && rank < 64) {
                int bp = __builtin_ctzll(w);
                w &= w - 1;
                sm.idxs[d][rank] = c*64 + bp;
                ++rank;
            }
            carry += total;
        }
        int cnt = carry < 64 ? carry : 64;
        int first = (cnt > 0) ? sm.idxs[d][0] : 0;
        if (ln >= cnt) sm.idxs[d][ln] = first;
    }

    // ---- aw2 A-fragments stay resident (16 VGPRs); aw3 is streamed in L3 --
    bf16x8 aw2[2][2];
    #pragma unroll
    for (int m = 0; m < 2; ++m) {
        int row = (wv*2+m)*16 + l15;
        #pragma unroll
        for (int kk = 0; kk < 2; ++kk)
            aw2[m][kk] = *(const bf16x8*)(w2p + row*64 + kk*32 + q*8);
    }

    __syncthreads();    // idxs visible; bm/cstart/ccnt dead -> h1/h2 may reuse

    // L1(d): lane ln recomputes rel_rot of idxs[d][ln] (exact contract(off)
    // arithmetic), then 16 channels of BN1-absorbed fma -> h1[ln][wv*16..].
    auto do_l1 = [&](int d) {
        int n = sm.idxs[d][ln];
        const float* p = pointcloud + (b*NPTS + n)*3;
        float x0, x1, x2;
        {
            #pragma clang fp contract(off)
            float rx = p[0] - sx, ry = p[1] - sy, rz = p[2] - sz;
            x0 = (rx*R00 + ry*R10) + rz*R20;
            x1 = (rx*R01 + ry*R11) + rz*R21;
            x2 = (rx*R02 + ry*R12) + rz*R22;
        }
        unsigned int pk[8];
        #pragma unroll
        for (int i = 0; i < 8; ++i) {
            int ch = wv*16 + i*2;
            float ha = fmaf(x0, sm.w1e[ch][0],
                       fmaf(x1, sm.w1e[ch][1],
                       fmaf(x2, sm.w1e[ch][2], sm.b1e[ch])));
            float hb = fmaf(x0, sm.w1e[ch+1][0],
                       fmaf(x1, sm.w1e[ch+1][1],
                       fmaf(x2, sm.w1e[ch+1][2], sm.b1e[ch+1])));
            pk[i] = pk2(fmaxf(ha, 0.f), fmaxf(hb, 0.f));
        }
        *(uint4*)&sm.u.b.h1[ln][wv*16 + 0] = make_uint4(pk[0], pk[1], pk[2], pk[3]);
        *(uint4*)&sm.u.b.h1[ln][wv*16 + 8] = make_uint4(pk[4], pk[5], pk[6], pk[7]);
    };

    do_l1(0);
    __syncthreads();

    for (int d = 0; d < 4; ++d) {
        // layer 2: M=128, K=64, N=64; acc init = BN2 bias (global, L2-hot)
        {
            f32x4 binit2[2];
            #pragma unroll
            for (int m = 0; m < 2; ++m)
                binit2[m] = *(const f32x4*)&b2e_g[(wv*2+m)*16 + q*4];
            #pragma unroll
            for (int nt = 0; nt < 4; ++nt) {
                int n = nt*16 + l15;
                bf16x8 b0 = *(const bf16x8*)&sm.u.b.h1[n][q*8];
                bf16x8 b1 = *(const bf16x8*)&sm.u.b.h1[n][32 + q*8];
                #pragma unroll
                for (int m = 0; m < 2; ++m) {
                    f32x4 acc = binit2[m];
                    acc = __builtin_amdgcn_mfma_f32_16x16x32_bf16(aw2[m][0], b0, acc, 0, 0, 0);
                    acc = __builtin_amdgcn_mfma_f32_16x16x32_bf16(aw2[m][1], b1, acc, 0, 0, 0);
                    int ch0 = (wv*2+m)*16 + q*4;
                    uint2 pkk;
                    pkk.x = pk2(fmaxf(acc[0], 0.f), fmaxf(acc[1], 0.f));
                    pkk.y = pk2(fmaxf(acc[2], 0.f), fmaxf(acc[3], 0.f));
                    *(uint2*)&sm.u.b.h2[n][ch0] = pkk;
                }
            }
        }
        __syncthreads();

        // layer 3: M=256, K=128; m-outer, aw3 row streamed from w3p
        // (L2-broadcast; frees the 64-VGPR resident block). acc init = BN3
        // bias (R15 semantics); ReLU folds into rm>=0.
        {
            float rm[4][4];
            #pragma unroll
            for (int m = 0; m < 4; ++m) {
                int row = (wv*4+m)*16 + l15;
                bf16x8 a0 = *(const bf16x8*)(w3p + row*128 +  0 + q*8);
                bf16x8 a1 = *(const bf16x8*)(w3p + row*128 + 32 + q*8);
                bf16x8 a2 = *(const bf16x8*)(w3p + row*128 + 64 + q*8);
                bf16x8 a3 = *(const bf16x8*)(w3p + row*128 + 96 + q*8);
                f32x4 binit3 = *(const f32x4*)&b3e_g[(wv*4+m)*16 + q*4];
                #pragma unroll
                for (int r = 0; r < 4; ++r) rm[m][r] = 0.f;
                #pragma unroll
                for (int nt = 0; nt < 4; ++nt) {
                    int n = nt*16 + l15;
                    bf16x8 bb0 = *(const bf16x8*)&sm.u.b.h2[n][ 0 + q*8];
                    bf16x8 bb1 = *(const bf16x8*)&sm.u.b.h2[n][32 + q*8];
                    bf16x8 bb2 = *(const bf16x8*)&sm.u.b.h2[n][64 + q*8];
                    bf16x8 bb3 = *(const bf16x8*)&sm.u.b.h2[n][96 + q*8];
                    f32x4 acc = binit3;
                    acc = __builtin_amdgcn_mfma_f32_16x16x32_bf16(a0, bb0, acc, 0, 0, 0);
                    acc = __builtin_amdgcn_mfma_f32_16x16x32_bf16(a1, bb1, acc, 0, 0, 0);
                    acc = __builtin_amdgcn_mfma_f32_16x16x32_bf16(a2, bb2, acc, 0, 0, 0);
                    acc = __builtin_amdgcn_mfma_f32_16x16x32_bf16(a3, bb3, acc, 0, 0, 0);
                    #pragma unroll
                    for (int r = 0; r < 4; ++r)
                        rm[m][r] = fmaxf(rm[m][r], acc[r]);
                }
            }

            if (d < 3) do_l1(d + 1);

            #pragma unroll
            for (int m = 0; m < 4; ++m) {
                #pragma unroll
                for (int r = 0; r < 4; ++r) {
                    float v = rm[m][r];
                    v = fmaxf(v, __shfl_xor(v, 1));
                    v = fmaxf(v, __shfl_xor(v, 2));
                    v = fmaxf(v, __shfl_xor(v, 4));
                    v = fmaxf(v, __shfl_xor(v, 8));
                    if (l15 == 0) {
                        int ch = (wv*4+m)*16 + q*4 + r;
                        out[((b*256 + ch)*1024 + s)*4 + d] = v;
                    }
                }
            }
        }
        if (d < 3) __syncthreads();
    }
}

extern "C" void kernel_launch(void* const* d_in, const int* in_sizes, int n_in,
                              void* d_out, int out_size, void* d_ws, size_t ws_size,
                              hipStream_t stream) {
    (void)in_sizes; (void)n_in; (void)out_size; (void)ws_size;
    const float* seed = (const float*)d_in[0];
    const float* pc   = (const float*)d_in[1];
    const float* rot  = (const float*)d_in[2];
    const float* w1   = (const float*)d_in[3];
    const float* g1   = (const float*)d_in[4];
    const float* be1  = (const float*)d_in[5];
    const float* mn1  = (const float*)d_in[6];
    const float* vr1  = (const float*)d_in[7];
    const float* w2   = (const float*)d_in[8];
    const float* g2   = (const float*)d_in[9];
    const float* be2  = (const float*)d_in[10];
    const float* mn2  = (const float*)d_in[11];
    const float* vr2  = (const float*)d_in[12];
    const float* w3   = (const float*)d_in[13];
    const float* g3   = (const float*)d_in[14];
    const float* be3  = (const float*)d_in[15];
    const float* mn3  = (const float*)d_in[16];
    const float* vr3  = (const float*)d_in[17];

    char* ws = (char*)d_ws;
    float4*         binned   = (float4*)(ws + WS_BINNED);
    unsigned int*   parthist = (unsigned int*)(ws + WS_PARTHIST);
    unsigned int*   counts   = (unsigned int*)(ws + WS_COUNTS);
    unsigned int*   offsets  = (unsigned int*)(ws + WS_OFFSETS);
    unsigned int*   flags    = (unsigned int*)(ws + WS_FLAGS);
    unsigned short* w2p      = (unsigned short*)(ws + WS_W2P);
    unsigned short* w3p      = (unsigned short*)(ws + WS_W3P);
    float*          w1e_g    = (float*)(ws + WS_W1E);
    float*          b1e_g    = (float*)(ws + WS_B1E);
    float*          b2e_g    = (float*)(ws + WS_B2E);
    float*          b3e_g    = (float*)(ws + WS_B3E);

    bin_kernel  <<<dim3(40),   dim3(512), 0, stream>>>(
        pc,
        w1, g1, be1, mn1, vr1,
        w2, g2, be2, mn2, vr2,
        w3, g3, be3, mn3, vr3,
        parthist, counts, offsets, flags, binned,
        w2p, w3p, w1e_g, b1e_g, b2e_g, b3e_g);
    fused_kernel<<<dim3(2048), dim3(256), 0, stream>>>(
        seed, pc, rot, counts, offsets, binned,
        w2p, w3p, w1e_g, b1e_g, b2e_g, b3e_g,
        (float*)d_out);
}